// Round 1
// baseline (309.324 us; speedup 1.0000x reference)
//
#include <hip/hip_runtime.h>
#include <hip/hip_bf16.h>

typedef float f32x4 __attribute__((ext_vector_type(4)));
typedef short s16x8 __attribute__((ext_vector_type(8)));
typedef __bf16 bf16x8 __attribute__((ext_vector_type(8)));
typedef unsigned short u16;

#define DEVI __device__ __forceinline__

static constexpr int    HW      = 16384;
static constexpr size_t BSTRIDE = (size_t)256 * HW;   // per-batch elems of a [256][HW] plane

// ---- workspace byte offsets ----
static constexpr size_t oXBT   = 0;                                    // bf16 [8][HW][256]; reused for qsT
static constexpr size_t oKEYS  = oXBT  + (size_t)8 * HW * 256 * 2;     // bf16 [8][256][HW]
static constexpr size_t oQS    = oKEYS + (size_t)8 * 256 * HW * 2;     // bf16 [8][256][HW] (softmaxed Q)
static constexpr size_t oVB    = oQS   + (size_t)8 * 256 * HW * 2;     // bf16 [8][256][HW]
static constexpr size_t oWK    = oVB   + (size_t)8 * 256 * HW * 2;     // bf16 [768][256]
static constexpr size_t oBIAS  = oWK   + (size_t)768 * 256 * 2;        // f32 [768]
static constexpr size_t oISE   = oBIAS + 4096;                         // f32 [8][256] inv row-sum-exp
static constexpr size_t oCTX   = oISE  + 8192;                         // f32 [64][32][32]
static constexpr size_t oMB    = oCTX  + (size_t)64 * 1024 * 4;        // bf16 [8][256][256]
static constexpr size_t oCPART = oMB   + (size_t)8 * 256 * 256 * 2;    // f32 [4096][1024]
static constexpr size_t oMPART = oCPART + (size_t)4096 * 1024 * 4;     // f32 [4][8][HW]

DEVI float bf2f(short x) {
  unsigned u = ((unsigned)(unsigned short)x) << 16;
  return __builtin_bit_cast(float, u);
}
DEVI u16 f2bf(float x) { return __builtin_bit_cast(u16, (__bf16)x); }

DEVI void gld16(const void* g, void* l) {
  __builtin_amdgcn_global_load_lds(
      (__attribute__((address_space(1))) void*)(g),
      (__attribute__((address_space(3))) void*)(l), 16, 0, 0);
}

// ---------------- prep: pack Wk|Wq|Wv -> bf16 [768][256], biases -> f32 [768] ----------------
__global__ __launch_bounds__(256) void k_prep(
    const float* __restrict__ Wk, const float* __restrict__ Wq, const float* __restrict__ Wv,
    const float* __restrict__ bk, const float* __restrict__ bq, const float* __restrict__ bv,
    u16* __restrict__ Wkqv, float* __restrict__ bias)
{
  int i = blockIdx.x * 256 + threadIdx.x;
  for (int p = i; p < 768 * 256; p += 64 * 256) {
    float v = (p < 65536) ? Wk[p] : (p < 131072 ? Wq[p - 65536] : Wv[p - 131072]);
    Wkqv[p] = f2bf(v);
  }
  if (i < 768) bias[i] = (i < 256) ? bk[i] : (i < 512 ? bq[i - 256] : bv[i - 512]);
}

// ---------------- transpose [8][256][HW] (f32 or bf16) -> bf16 [8][HW][256] ----------------
template<int F32IN>
__global__ __launch_bounds__(256) void k_transpose(const void* __restrict__ in_, u16* __restrict__ out)
{
  __shared__ u16 lds[64 * 256];
  const int t = threadIdx.x;
  const int n = blockIdx.y;
  const int s0 = blockIdx.x * 64;
  if constexpr (F32IN) {
    const float* src = (const float*)in_ + ((size_t)n * 256 + t) * HW + s0;
    #pragma unroll
    for (int i = 0; i < 16; ++i) {
      f32x4 v = *(const f32x4*)(src + i * 4);
      #pragma unroll
      for (int j = 0; j < 4; ++j) lds[(i * 4 + j) * 256 + t] = f2bf(v[j]);
    }
  } else {
    const u16* src = (const u16*)in_ + ((size_t)n * 256 + t) * HW + s0;
    #pragma unroll
    for (int i = 0; i < 8; ++i) {
      s16x8 v = *(const s16x8*)(src + i * 8);
      #pragma unroll
      for (int j = 0; j < 8; ++j) lds[(i * 8 + j) * 256 + t] = (u16)v[j];
    }
  }
  __syncthreads();
  s16x8* gp = (s16x8*)(out + (size_t)n * BSTRIDE + (size_t)s0 * 256);
  const s16x8* lp = (const s16x8*)lds;
  #pragma unroll
  for (int i = 0; i < 8; ++i) gp[t + i * 256] = lp[t + i * 256];
}

// ---------------- MFMA GEMM: out[m][s] = A[m][k] * Bt[s][k] + bias ----------------
// MODE 0: bf16 out; MODE 1: per-head(32-row) softmax over m, bf16 out; MODE 2: f32 out
template<int MODE>
__global__ __launch_bounds__(256) void k_gemm(
    const u16* __restrict__ A, long a_bstride,
    const u16* __restrict__ Bt,
    const float* __restrict__ bias,
    void* __restrict__ Out)
{
  __shared__ u16 Al[2][4096];
  __shared__ u16 Bl[2][4096];
  const int t = threadIdx.x;
  const int n = blockIdx.z;
  const int m0 = blockIdx.y * 128;
  const int s0 = blockIdx.x * 128;
  const int lane = t & 63;
  const int l15 = lane & 15, l4 = lane >> 4;
  const int wv = t >> 6;
  const int wm = (wv & 1) * 64, wn = (wv >> 1) * 64;
  const u16* Ab = A + (size_t)n * a_bstride + (size_t)m0 * 256;
  const u16* Bb = Bt + (size_t)n * BSTRIDE + (size_t)s0 * 256;
  const int ar = t >> 2, ac = (t & 3) * 8;

  f32x4 acc[4][4] = {};

  auto stage = [&](int buf, int k0) {
    gld16(Ab + (size_t)ar * 256 + k0 + ac,        &Al[buf][t * 8]);
    gld16(Ab + (size_t)(ar + 64) * 256 + k0 + ac, &Al[buf][2048 + t * 8]);
    gld16(Bb + (size_t)ar * 256 + k0 + ac,        &Bl[buf][t * 8]);
    gld16(Bb + (size_t)(ar + 64) * 256 + k0 + ac, &Bl[buf][2048 + t * 8]);
  };

  stage(0, 0);
  __syncthreads();
  #pragma unroll
  for (int kt = 0; kt < 8; ++kt) {
    const int buf = kt & 1;
    if (kt < 7) stage(buf ^ 1, (kt + 1) * 32);
    bf16x8 af[4], bff[4];
    #pragma unroll
    for (int g = 0; g < 4; ++g) {
      af[g]  = *(const bf16x8*)&Al[buf][(wm + g * 16 + l15) * 32 + l4 * 8];
      bff[g] = *(const bf16x8*)&Bl[buf][(wn + g * 16 + l15) * 32 + l4 * 8];
    }
    #pragma unroll
    for (int mg = 0; mg < 4; ++mg)
      #pragma unroll
      for (int ng = 0; ng < 4; ++ng)
        acc[mg][ng] = __builtin_amdgcn_mfma_f32_16x16x32_bf16(af[mg], bff[ng], acc[mg][ng], 0, 0, 0);
    __syncthreads();
  }

  #pragma unroll
  for (int mg = 0; mg < 4; ++mg)
    #pragma unroll
    for (int r = 0; r < 4; ++r) {
      const float bb = bias[m0 + wm + mg * 16 + l4 * 4 + r];
      #pragma unroll
      for (int ng = 0; ng < 4; ++ng) acc[mg][ng][r] += bb;
    }

  if constexpr (MODE == 1) {
    // softmax over the 32 m-rows of each head (head boundary = 32 rows; wave covers 2 heads)
    #pragma unroll
    for (int hh = 0; hh < 2; ++hh)
      #pragma unroll
      for (int ng = 0; ng < 4; ++ng) {
        float s = 0.f;
        #pragma unroll
        for (int mg = hh * 2; mg < hh * 2 + 2; ++mg)
          #pragma unroll
          for (int r = 0; r < 4; ++r) { const float e = __expf(acc[mg][ng][r]); acc[mg][ng][r] = e; s += e; }
        s += __shfl_xor(s, 16);
        s += __shfl_xor(s, 32);
        const float inv = 1.f / s;
        #pragma unroll
        for (int mg = hh * 2; mg < hh * 2 + 2; ++mg)
          #pragma unroll
          for (int r = 0; r < 4; ++r) acc[mg][ng][r] *= inv;
      }
  }

  if constexpr (MODE == 2) {
    float* O = (float*)Out + (size_t)n * BSTRIDE;
    #pragma unroll
    for (int mg = 0; mg < 4; ++mg)
      #pragma unroll
      for (int r = 0; r < 4; ++r) {
        const size_t row = m0 + wm + mg * 16 + l4 * 4 + r;
        float* op = O + row * HW + s0 + wn + l15;
        #pragma unroll
        for (int ng = 0; ng < 4; ++ng) op[ng * 16] = acc[mg][ng][r];
      }
  } else {
    u16* O = (u16*)Out + (size_t)n * BSTRIDE;
    #pragma unroll
    for (int mg = 0; mg < 4; ++mg)
      #pragma unroll
      for (int r = 0; r < 4; ++r) {
        const size_t row = m0 + wm + mg * 16 + l4 * 4 + r;
        u16* op = O + row * HW + s0 + wn + l15;
        #pragma unroll
        for (int ng = 0; ng < 4; ++ng) op[ng * 16] = f2bf(acc[mg][ng][r]);
      }
  }
}

// ---------------- per-(n,k) inverse sum of exp over s ----------------
__global__ __launch_bounds__(256) void k_rowsum(const u16* __restrict__ keys, float* __restrict__ inv_se)
{
  const int k = blockIdx.x, n = blockIdx.y, t = threadIdx.x;
  const u16* row = keys + ((size_t)n * 256 + k) * HW;
  float s = 0.f;
  #pragma unroll
  for (int i = 0; i < 8; ++i) {
    s16x8 v = *(const s16x8*)(row + t * 8 + i * 2048);
    #pragma unroll
    for (int j = 0; j < 8; ++j) s += __expf(bf2f(v[j]));
  }
  #pragma unroll
  for (int m = 1; m < 64; m <<= 1) s += __shfl_xor(s, m);
  __shared__ float red[4];
  if ((t & 63) == 0) red[t >> 6] = s;
  __syncthreads();
  if (t == 0) inv_se[n * 256 + k] = 1.f / (red[0] + red[1] + red[2] + red[3]);
}

// ---------------- ctx split-K partials: [nh][chunk] over 256 s each, MFMA direct-from-global ----------------
__global__ __launch_bounds__(64) void k_ctx_part(
    const u16* __restrict__ keys, const u16* __restrict__ vbuf, float* __restrict__ cpart)
{
  const int blk = blockIdx.x;            // nh*64 + chunk
  const int chunk = blk & 63, nh = blk >> 6;
  const int h = nh & 7, n = nh >> 3;
  const int lane = threadIdx.x;
  const int l15 = lane & 15, l4 = lane >> 4;
  const u16* kb = keys + ((size_t)n * 256 + h * 32) * HW;
  const u16* vv = vbuf + ((size_t)n * 256 + h * 32) * HW;
  f32x4 acc[2][2] = {};
  const int sbase = chunk * 256 + l4 * 8;
  #pragma unroll
  for (int ks = 0; ks < 8; ++ks) {
    const int sb = sbase + ks * 32;
    bf16x8 ef[2], vf[2];
    #pragma unroll
    for (int g = 0; g < 2; ++g) {
      s16x8 kv = *(const s16x8*)(kb + (size_t)(g * 16 + l15) * HW + sb);
      bf16x8 e;
      #pragma unroll
      for (int j = 0; j < 8; ++j) e[j] = (__bf16)__expf(bf2f(kv[j]));
      ef[g] = e;
      vf[g] = *(const bf16x8*)(vv + (size_t)(g * 16 + l15) * HW + sb);
    }
    #pragma unroll
    for (int a = 0; a < 2; ++a)
      #pragma unroll
      for (int b = 0; b < 2; ++b)
        acc[a][b] = __builtin_amdgcn_mfma_f32_16x16x32_bf16(ef[a], vf[b], acc[a][b], 0, 0, 0);
  }
  float* op = cpart + (size_t)blk * 1024;
  #pragma unroll
  for (int a = 0; a < 2; ++a)
    #pragma unroll
    for (int b = 0; b < 2; ++b)
      #pragma unroll
      for (int r = 0; r < 4; ++r)
        op[(a * 16 + l4 * 4 + r) * 32 + b * 16 + l15] = acc[a][b][r];
}

// ---------------- reduce ctx partials, normalize; also emit context_last (h==7) ----------------
__global__ __launch_bounds__(256) void k_ctx_reduce(
    const float* __restrict__ cpart, const float* __restrict__ inv_se,
    float* __restrict__ ctx, float* __restrict__ dctx)
{
  const int nh = blockIdx.x, n = nh >> 3, h = nh & 7, t = threadIdx.x;
  f32x4 a = {};
  for (int c = 0; c < 64; ++c) a += *(const f32x4*)(cpart + ((size_t)nh * 64 + c) * 1024 + t * 4);
  const float inv = inv_se[n * 256 + h * 32 + (t >> 3)];
  a *= inv;
  *(f32x4*)(ctx + (size_t)nh * 1024 + t * 4) = a;
  if (h == 7) *(f32x4*)(dctx + (size_t)n * 1024 + t * 4) = a;
}

// ---------------- M[n][o][h*32+k] = sum_v Wr[o][h*32+v] * ctx[n][h][k][v] ----------------
__global__ __launch_bounds__(256) void k_mmat(
    const float* __restrict__ ctx, const float* __restrict__ Wr, u16* __restrict__ Mb)
{
  const int nh = blockIdx.x, n = nh >> 3, h = nh & 7, o = threadIdx.x;
  __shared__ float cl[1024];
  #pragma unroll
  for (int i = 0; i < 4; ++i) cl[o + i * 256] = ctx[(size_t)nh * 1024 + o + i * 256];
  __syncthreads();
  float wr[32];
  const float* wp = Wr + (size_t)o * 256 + h * 32;
  #pragma unroll
  for (int v = 0; v < 32; ++v) wr[v] = wp[v];
  u16* mp = Mb + ((size_t)n * 256 + o) * 256 + h * 32;
  #pragma unroll 4
  for (int k = 0; k < 32; ++k) {
    float s = 0.f;
    #pragma unroll
    for (int v = 0; v < 32; ++v) s += wr[v] * cl[k * 32 + v];
    mp[k] = f2bf(s);
  }
}

// ---------------- attention_map partials (k-split 4) and reduce ----------------
__global__ __launch_bounds__(64) void k_map_part(
    const u16* __restrict__ keys, const float* __restrict__ inv_se, float* __restrict__ mpart)
{
  const int st = blockIdx.x, kq = blockIdx.y, n = blockIdx.z, t = threadIdx.x;
  const int s0 = st * 512 + t * 8;
  const u16* kb = keys + (size_t)n * 256 * HW;
  const float* ip = inv_se + n * 256 + kq * 64;
  f32x4 a[2] = {};
  #pragma unroll 4
  for (int kk = 0; kk < 64; ++kk) {
    const int k = kq * 64 + kk;
    const float iv = ip[kk];
    s16x8 v = *(const s16x8*)(kb + (size_t)k * HW + s0);
    #pragma unroll
    for (int j = 0; j < 8; ++j) a[j >> 2][j & 3] += __expf(bf2f(v[j])) * iv;
  }
  float* mp = mpart + ((size_t)kq * 8 + n) * HW + s0;
  *(f32x4*)mp = a[0];
  *(f32x4*)(mp + 4) = a[1];
}

__global__ __launch_bounds__(256) void k_map_reduce(const float* __restrict__ mpart, float* __restrict__ dmap)
{
  const int i = blockIdx.x * 256 + threadIdx.x;   // 32768 threads, f32x4 each
  f32x4 a = {};
  #pragma unroll
  for (int kq = 0; kq < 4; ++kq) a += *(const f32x4*)(mpart + (size_t)kq * 131072 + (size_t)i * 4);
  a *= (1.0f / 256.0f);
  *(f32x4*)(dmap + (size_t)i * 4) = a;
}

extern "C" void kernel_launch(void* const* d_in, const int* in_sizes, int n_in,
                              void* d_out, int out_size, void* d_ws, size_t ws_size,
                              hipStream_t stream)
{
  (void)in_sizes; (void)n_in; (void)out_size; (void)ws_size;
  const float* x  = (const float*)d_in[0];
  const float* Wk = (const float*)d_in[1];
  const float* bk = (const float*)d_in[2];
  const float* Wq = (const float*)d_in[3];
  const float* bq = (const float*)d_in[4];
  const float* Wv = (const float*)d_in[5];
  const float* bv = (const float*)d_in[6];
  const float* Wr = (const float*)d_in[7];
  const float* br = (const float*)d_in[8];

  char* ws = (char*)d_ws;
  u16*   xbT  = (u16*)(ws + oXBT);
  u16*   keys = (u16*)(ws + oKEYS);
  u16*   qs   = (u16*)(ws + oQS);
  u16*   vbuf = (u16*)(ws + oVB);
  u16*   Wkqv = (u16*)(ws + oWK);
  float* bias = (float*)(ws + oBIAS);
  float* ise  = (float*)(ws + oISE);
  float* ctx  = (float*)(ws + oCTX);
  u16*   Mb   = (u16*)(ws + oMB);
  float* cpart= (float*)(ws + oCPART);
  float* mpart= (float*)(ws + oMPART);

  float* attn = (float*)d_out;                    // [8][256][HW]
  float* dctx = (float*)d_out + 33554432;         // [8][32][32]
  float* dmap = (float*)d_out + 33562624;         // [8][HW]

  k_prep<<<64, 256, 0, stream>>>(Wk, Wq, Wv, bk, bq, bv, Wkqv, bias);
  k_transpose<1><<<dim3(256, 8), 256, 0, stream>>>(x, xbT);
  k_gemm<0><<<dim3(128, 2, 8), 256, 0, stream>>>(Wkqv,             0, xbT, bias,       keys);
  k_gemm<1><<<dim3(128, 2, 8), 256, 0, stream>>>(Wkqv + 256 * 256, 0, xbT, bias + 256, qs);
  k_gemm<0><<<dim3(128, 2, 8), 256, 0, stream>>>(Wkqv + 512 * 256, 0, xbT, bias + 512, vbuf);
  k_rowsum<<<dim3(256, 8), 256, 0, stream>>>(keys, ise);
  k_ctx_part<<<4096, 64, 0, stream>>>(keys, vbuf, cpart);
  k_ctx_reduce<<<64, 256, 0, stream>>>(cpart, ise, ctx, dctx);
  k_mmat<<<64, 256, 0, stream>>>(ctx, Wr, Mb);
  k_map_part<<<dim3(32, 4, 8), 64, 0, stream>>>(keys, ise, mpart);
  k_map_reduce<<<128, 256, 0, stream>>>(mpart, dmap);
  // transpose softmaxed Q into the (now dead) xbT region: [s][m] layout for the final GEMM
  k_transpose<0><<<dim3(256, 8), 256, 0, stream>>>(qs, xbT);
  k_gemm<2><<<dim3(128, 2, 8), 256, 0, stream>>>(Mb, 256 * 256, xbT, br, attn);
}

// Round 2
// 289.715 us; speedup vs baseline: 1.0677x; 1.0677x over previous
//
#include <hip/hip_runtime.h>
#include <hip/hip_bf16.h>

typedef float f32x4 __attribute__((ext_vector_type(4)));
typedef short s16x8 __attribute__((ext_vector_type(8)));
typedef __bf16 bf16x8 __attribute__((ext_vector_type(8)));
typedef unsigned short u16;

#define DEVI __device__ __forceinline__

static constexpr int    HW      = 16384;
static constexpr size_t BSTRIDE = (size_t)256 * HW;

// ---- workspace byte offsets ----
static constexpr size_t oXBT   = 0;                                    // bf16 [8][HW][256]
static constexpr size_t oEK    = oXBT  + (size_t)8 * HW * 256 * 2;     // bf16 [8][256][HW] exp(keys)
static constexpr size_t oQT    = oEK   + (size_t)8 * 256 * HW * 2;     // bf16 [8][HW][256] softmaxed Q, transposed
static constexpr size_t oVB    = oQT   + (size_t)8 * HW * 256 * 2;     // bf16 [8][256][HW]
static constexpr size_t oWK    = oVB   + (size_t)8 * 256 * HW * 2;     // bf16 [768][256]
static constexpr size_t oBIAS  = oWK   + (size_t)768 * 256 * 2;        // f32 [768]
static constexpr size_t oISE   = oBIAS + 4096;                         // f32 [8][256] inv row-sum-exp
static constexpr size_t oPS    = oISE  + 8192;                         // f32 [256][8][256] rowsum partials
static constexpr size_t oCTX   = oPS   + (size_t)256 * 2048 * 4;       // f32 [64][32][32]
static constexpr size_t oMB    = oCTX  + (size_t)64 * 1024 * 4;        // bf16 [8][256][256]
static constexpr size_t oCPART = oMB   + (size_t)8 * 256 * 256 * 2;    // f32 [4096][1024]
static constexpr size_t oMPART = oCPART + (size_t)4096 * 1024 * 4;     // f32 [8][8][HW]

DEVI float bf2f(short x) {
  unsigned u = ((unsigned)(unsigned short)x) << 16;
  return __builtin_bit_cast(float, u);
}
DEVI u16 f2bf(float x) { return __builtin_bit_cast(u16, (__bf16)x); }

DEVI void gld16(const void* g, void* l) {
  __builtin_amdgcn_global_load_lds(
      (__attribute__((address_space(1))) void*)(g),
      (__attribute__((address_space(3))) void*)(l), 16, 0, 0);
}

// ---------------- prep: pack Wk|Wq|Wv -> bf16 [768][256], biases -> f32 [768] ----------------
__global__ __launch_bounds__(256) void k_prep(
    const float* __restrict__ Wk, const float* __restrict__ Wq, const float* __restrict__ Wv,
    const float* __restrict__ bk, const float* __restrict__ bq, const float* __restrict__ bv,
    u16* __restrict__ Wkqv, float* __restrict__ bias)
{
  int i = blockIdx.x * 256 + threadIdx.x;
  for (int p = i; p < 768 * 256; p += 64 * 256) {
    float v = (p < 65536) ? Wk[p] : (p < 131072 ? Wq[p - 65536] : Wv[p - 131072]);
    Wkqv[p] = f2bf(v);
  }
  if (i < 768) bias[i] = (i < 256) ? bk[i] : (i < 512 ? bq[i - 256] : bv[i - 512]);
}

// ---------------- transpose x [8][256][HW] f32 -> bf16 [8][HW][256] ----------------
__global__ __launch_bounds__(256) void k_transpose(const float* __restrict__ in_, u16* __restrict__ out)
{
  __shared__ u16 lds[64 * 256];
  const int t = threadIdx.x;
  const int n = blockIdx.y;
  const int s0 = blockIdx.x * 64;
  const float* src = in_ + ((size_t)n * 256 + t) * HW + s0;
  #pragma unroll
  for (int i = 0; i < 16; ++i) {
    f32x4 v = *(const f32x4*)(src + i * 4);
    #pragma unroll
    for (int j = 0; j < 4; ++j) lds[(i * 4 + j) * 256 + t] = f2bf(v[j]);
  }
  __syncthreads();
  s16x8* gp = (s16x8*)(out + (size_t)n * BSTRIDE + (size_t)s0 * 256);
  const s16x8* lp = (const s16x8*)lds;
  #pragma unroll
  for (int i = 0; i < 8; ++i) gp[t + i * 256] = lp[t + i * 256];
}

// ---------------- fused projection GEMM: [768]x[256]x[HW] per batch ----------------
// mb 0,1: exp(keys) -> ek + rowsum partials; mb 2,3: head-softmax Q -> qT (transposed);
// mb 4,5: values -> vb
__global__ __launch_bounds__(256) void k_proj(
    const u16* __restrict__ W, const u16* __restrict__ xbT, const float* __restrict__ bias,
    u16* __restrict__ ek, u16* __restrict__ qT, u16* __restrict__ vb, float* __restrict__ ps)
{
  __shared__ u16 smem[17408];           // staging: [2][4096] A | [2][4096] B; epilogue: 128x136 tile
  u16* Al = smem;
  u16* Bl = smem + 8192;
  const int t = threadIdx.x;
  const int L = blockIdx.x;
  const int n  = L & 7;                 // one batch per XCD (6144 = 8 * 768, bijective)
  const int idx = L >> 3;
  const int mb = idx % 6;               // m-blocks adjacent -> same XCD L2 reuses B-tile
  const int sb = idx / 6;
  const int m0 = mb * 128, s0 = sb * 128;
  const int lane = t & 63;
  const int l15 = lane & 15, l4 = lane >> 4;
  const int wv = t >> 6;
  const int wm = (wv & 1) * 64, wn = (wv >> 1) * 64;
  const u16* Ab = W + (size_t)m0 * 256;
  const u16* Bb = xbT + (size_t)n * BSTRIDE + (size_t)s0 * 256;
  const int ar = t >> 2, ac = (t & 3) * 8;

  f32x4 acc[4][4] = {};

  auto stage = [&](int buf, int k0) {
    gld16(Ab + (size_t)ar * 256 + k0 + ac,        Al + buf * 4096 + t * 8);
    gld16(Ab + (size_t)(ar + 64) * 256 + k0 + ac, Al + buf * 4096 + 2048 + t * 8);
    gld16(Bb + (size_t)ar * 256 + k0 + ac,        Bl + buf * 4096 + t * 8);
    gld16(Bb + (size_t)(ar + 64) * 256 + k0 + ac, Bl + buf * 4096 + 2048 + t * 8);
  };

  stage(0, 0);
  __syncthreads();
  #pragma unroll
  for (int kt = 0; kt < 8; ++kt) {
    const int buf = kt & 1;
    if (kt < 7) stage(buf ^ 1, (kt + 1) * 32);
    bf16x8 af[4], bff[4];
    #pragma unroll
    for (int g = 0; g < 4; ++g) {
      af[g]  = *(const bf16x8*)&Al[buf * 4096 + (wm + g * 16 + l15) * 32 + l4 * 8];
      bff[g] = *(const bf16x8*)&Bl[buf * 4096 + (wn + g * 16 + l15) * 32 + l4 * 8];
    }
    #pragma unroll
    for (int mg = 0; mg < 4; ++mg)
      #pragma unroll
      for (int ng = 0; ng < 4; ++ng)
        acc[mg][ng] = __builtin_amdgcn_mfma_f32_16x16x32_bf16(af[mg], bff[ng], acc[mg][ng], 0, 0, 0);
    __syncthreads();
  }

  #pragma unroll
  for (int mg = 0; mg < 4; ++mg)
    #pragma unroll
    for (int r = 0; r < 4; ++r) {
      const float bb = bias[m0 + wm + mg * 16 + l4 * 4 + r];
      #pragma unroll
      for (int ng = 0; ng < 4; ++ng) acc[mg][ng][r] += bb;
    }

  const int rowBase = (mb & 1) * 128;

  if (mb < 2) {
    // keys: exp in f32, deterministic per-(block,wave-half) row-sum partials, bf16 store
    #pragma unroll
    for (int mg = 0; mg < 4; ++mg)
      #pragma unroll
      for (int r = 0; r < 4; ++r) {
        float s_ = 0.f;
        #pragma unroll
        for (int ng = 0; ng < 4; ++ng) {
          const float e = __expf(acc[mg][ng][r]);
          acc[mg][ng][r] = e; s_ += e;
        }
        s_ += __shfl_xor(s_, 1); s_ += __shfl_xor(s_, 2);
        s_ += __shfl_xor(s_, 4); s_ += __shfl_xor(s_, 8);
        if (l15 == 0) {
          const int row = rowBase + wm + mg * 16 + l4 * 4 + r;
          ps[((size_t)(sb * 2 + (wn >> 6))) * 2048 + n * 256 + row] = s_;
        }
      }
    u16* O = ek + (size_t)n * BSTRIDE;
    #pragma unroll
    for (int mg = 0; mg < 4; ++mg)
      #pragma unroll
      for (int r = 0; r < 4; ++r) {
        const size_t row = rowBase + wm + mg * 16 + l4 * 4 + r;
        u16* op = O + row * HW + s0 + wn + l15;
        #pragma unroll
        for (int ng = 0; ng < 4; ++ng) op[ng * 16] = f2bf(acc[mg][ng][r]);
      }
  } else if (mb < 4) {
    // queries: softmax over each 32-row head, then transposed store via padded LDS tile
    #pragma unroll
    for (int hh = 0; hh < 2; ++hh)
      #pragma unroll
      for (int ng = 0; ng < 4; ++ng) {
        float s = 0.f;
        #pragma unroll
        for (int mg = hh * 2; mg < hh * 2 + 2; ++mg)
          #pragma unroll
          for (int r = 0; r < 4; ++r) { const float e = __expf(acc[mg][ng][r]); acc[mg][ng][r] = e; s += e; }
        s += __shfl_xor(s, 16);
        s += __shfl_xor(s, 32);
        const float inv = 1.f / s;
        #pragma unroll
        for (int mg = hh * 2; mg < hh * 2 + 2; ++mg)
          #pragma unroll
          for (int r = 0; r < 4; ++r) acc[mg][ng][r] *= inv;
      }
    // acc[mg][ng][r] is value at (m = wm+mg*16+l4*4+r, s = wn+ng*16+l15); write [s][m] tile
    #pragma unroll
    for (int mg = 0; mg < 4; ++mg)
      #pragma unroll
      for (int ng = 0; ng < 4; ++ng)
        #pragma unroll
        for (int r = 0; r < 4; ++r) {
          const int srow = wn + ng * 16 + l15;
          const int mcol = wm + mg * 16 + l4 * 4 + r;
          smem[srow * 136 + mcol] = f2bf(acc[mg][ng][r]);
        }
    __syncthreads();
    u16* O = qT + (size_t)n * BSTRIDE + (size_t)s0 * 256 + rowBase;
    #pragma unroll
    for (int it = 0; it < 8; ++it) {
      const int row = it * 16 + (t >> 4);
      *(s16x8*)(O + (size_t)row * 256 + (t & 15) * 8) = *(const s16x8*)&smem[row * 136 + (t & 15) * 8];
    }
  } else {
    // values: plain bf16 store
    u16* O = vb + (size_t)n * BSTRIDE;
    #pragma unroll
    for (int mg = 0; mg < 4; ++mg)
      #pragma unroll
      for (int r = 0; r < 4; ++r) {
        const size_t row = rowBase + wm + mg * 16 + l4 * 4 + r;
        u16* op = O + row * HW + s0 + wn + l15;
        #pragma unroll
        for (int ng = 0; ng < 4; ++ng) op[ng * 16] = f2bf(acc[mg][ng][r]);
      }
  }
}

// ---------------- reduce rowsum partials -> inverse ----------------
__global__ __launch_bounds__(256) void k_inv(const float* __restrict__ ps, float* __restrict__ ise)
{
  const int i = blockIdx.x * 256 + threadIdx.x;   // 2048
  float s = 0.f;
  for (int b = 0; b < 256; ++b) s += ps[(size_t)b * 2048 + i];
  ise[i] = 1.f / s;
}

// ---------------- ctx split-K partials + fused attention-map partials ----------------
__global__ __launch_bounds__(64) void k_ctx_part(
    const u16* __restrict__ ek, const u16* __restrict__ vb, const float* __restrict__ ise,
    float* __restrict__ cpart, float* __restrict__ mpart)
{
  const int blk = blockIdx.x;            // nh*64 + chunk
  const int chunk = blk & 63, nh = blk >> 6;
  const int h = nh & 7, n = nh >> 3;
  const int lane = threadIdx.x;
  const int l15 = lane & 15, l4 = lane >> 4;
  const u16* kb = ek + ((size_t)n * 256 + h * 32) * HW;
  const u16* vv = vb + ((size_t)n * 256 + h * 32) * HW;
  const float iv0 = ise[n * 256 + h * 32 + l15];
  const float iv1 = ise[n * 256 + h * 32 + 16 + l15];
  f32x4 acc[2][2] = {};
  float macc[8][8] = {};
  const int sbase = chunk * 256 + l4 * 8;
  #pragma unroll
  for (int ks = 0; ks < 8; ++ks) {
    const int sb = sbase + ks * 32;
    bf16x8 ef[2], vf[2];
    #pragma unroll
    for (int g = 0; g < 2; ++g) {
      ef[g] = *(const bf16x8*)(kb + (size_t)(g * 16 + l15) * HW + sb);
      vf[g] = *(const bf16x8*)(vv + (size_t)(g * 16 + l15) * HW + sb);
    }
    #pragma unroll
    for (int j = 0; j < 8; ++j)
      macc[ks][j] = fmaf(iv0, (float)ef[0][j], fmaf(iv1, (float)ef[1][j], macc[ks][j]));
    #pragma unroll
    for (int a = 0; a < 2; ++a)
      #pragma unroll
      for (int b = 0; b < 2; ++b)
        acc[a][b] = __builtin_amdgcn_mfma_f32_16x16x32_bf16(ef[a], vf[b], acc[a][b], 0, 0, 0);
  }
  float* op = cpart + (size_t)blk * 1024;
  #pragma unroll
  for (int a = 0; a < 2; ++a)
    #pragma unroll
    for (int b = 0; b < 2; ++b)
      #pragma unroll
      for (int r = 0; r < 4; ++r)
        op[(a * 16 + l4 * 4 + r) * 32 + b * 16 + l15] = acc[a][b][r];
  // reduce map partials across the 16 k-lanes
  #pragma unroll
  for (int ks = 0; ks < 8; ++ks)
    #pragma unroll
    for (int j = 0; j < 8; ++j) {
      float v = macc[ks][j];
      v += __shfl_xor(v, 1); v += __shfl_xor(v, 2);
      v += __shfl_xor(v, 4); v += __shfl_xor(v, 8);
      macc[ks][j] = v;
    }
  if (l15 == 0) {
    float* mp = mpart + ((size_t)h * 8 + n) * HW + sbase;
    #pragma unroll
    for (int ks = 0; ks < 8; ++ks) {
      f32x4 a = {macc[ks][0], macc[ks][1], macc[ks][2], macc[ks][3]};
      f32x4 b = {macc[ks][4], macc[ks][5], macc[ks][6], macc[ks][7]};
      *(f32x4*)(mp + ks * 32)     = a;
      *(f32x4*)(mp + ks * 32 + 4) = b;
    }
  }
}

// ---------------- reduce ctx partials, normalize; emit context_last (h==7) ----------------
__global__ __launch_bounds__(256) void k_ctx_reduce(
    const float* __restrict__ cpart, const float* __restrict__ ise,
    float* __restrict__ ctx, float* __restrict__ dctx)
{
  const int nh = blockIdx.x, n = nh >> 3, h = nh & 7, t = threadIdx.x;
  f32x4 a = {};
  for (int c = 0; c < 64; ++c) a += *(const f32x4*)(cpart + ((size_t)nh * 64 + c) * 1024 + t * 4);
  const float inv = ise[n * 256 + h * 32 + (t >> 3)];
  a *= inv;
  *(f32x4*)(ctx + (size_t)nh * 1024 + t * 4) = a;
  if (h == 7) *(f32x4*)(dctx + (size_t)n * 1024 + t * 4) = a;
}

// ---------------- M[n][o][h*32+k] = sum_v Wr[o][h*32+v] * ctx[n][h][k][v] ----------------
__global__ __launch_bounds__(256) void k_mmat(
    const float* __restrict__ ctx, const float* __restrict__ Wr, u16* __restrict__ Mb)
{
  const int nh = blockIdx.x, n = nh >> 3, h = nh & 7, o = threadIdx.x;
  __shared__ float cl[1024];
  #pragma unroll
  for (int i = 0; i < 4; ++i) cl[o + i * 256] = ctx[(size_t)nh * 1024 + o + i * 256];
  __syncthreads();
  float wr[32];
  const float* wp = Wr + (size_t)o * 256 + h * 32;
  #pragma unroll
  for (int v = 0; v < 32; ++v) wr[v] = wp[v];
  u16* mp = Mb + ((size_t)n * 256 + o) * 256 + h * 32;
  #pragma unroll 4
  for (int k = 0; k < 32; ++k) {
    float s = 0.f;
    #pragma unroll
    for (int v = 0; v < 32; ++v) s += wr[v] * cl[k * 32 + v];
    mp[k] = f2bf(s);
  }
}

// ---------------- attention_map: sum 8 head partials, /256 ----------------
__global__ __launch_bounds__(256) void k_map_reduce(const float* __restrict__ mpart, float* __restrict__ dmap)
{
  const int i = blockIdx.x * 256 + threadIdx.x;   // 32768 threads, f32x4 each
  f32x4 a = {};
  #pragma unroll
  for (int h = 0; h < 8; ++h) a += *(const f32x4*)(mpart + (size_t)h * 131072 + (size_t)i * 4);
  a *= (1.0f / 256.0f);
  *(f32x4*)(dmap + (size_t)i * 4) = a;
}

// ---------------- final GEMM: attn[o][s] = sum_m M[o][m] * Q[s][m] + br, f32 out ----------------
__global__ __launch_bounds__(256) void k_attn(
    const u16* __restrict__ Mb, const u16* __restrict__ qT, const float* __restrict__ br,
    float* __restrict__ Out)
{
  __shared__ u16 Al[2][4096];
  __shared__ u16 Bl[2][4096];
  const int t = threadIdx.x;
  const int L = blockIdx.x;
  const int n = L & 7;
  const int idx = L >> 3;
  const int m0 = (idx & 1) * 128;
  const int s0 = (idx >> 1) * 128;
  const int lane = t & 63;
  const int l15 = lane & 15, l4 = lane >> 4;
  const int wv = t >> 6;
  const int wm = (wv & 1) * 64, wn = (wv >> 1) * 64;
  const u16* Ab = Mb + (size_t)n * 65536 + (size_t)m0 * 256;
  const u16* Bb = qT + (size_t)n * BSTRIDE + (size_t)s0 * 256;
  const int ar = t >> 2, ac = (t & 3) * 8;

  f32x4 acc[4][4] = {};

  auto stage = [&](int buf, int k0) {
    gld16(Ab + (size_t)ar * 256 + k0 + ac,        &Al[buf][t * 8]);
    gld16(Ab + (size_t)(ar + 64) * 256 + k0 + ac, &Al[buf][2048 + t * 8]);
    gld16(Bb + (size_t)ar * 256 + k0 + ac,        &Bl[buf][t * 8]);
    gld16(Bb + (size_t)(ar + 64) * 256 + k0 + ac, &Bl[buf][2048 + t * 8]);
  };

  stage(0, 0);
  __syncthreads();
  #pragma unroll
  for (int kt = 0; kt < 8; ++kt) {
    const int buf = kt & 1;
    if (kt < 7) stage(buf ^ 1, (kt + 1) * 32);
    bf16x8 af[4], bff[4];
    #pragma unroll
    for (int g = 0; g < 4; ++g) {
      af[g]  = *(const bf16x8*)&Al[buf][(wm + g * 16 + l15) * 32 + l4 * 8];
      bff[g] = *(const bf16x8*)&Bl[buf][(wn + g * 16 + l15) * 32 + l4 * 8];
    }
    #pragma unroll
    for (int mg = 0; mg < 4; ++mg)
      #pragma unroll
      for (int ng = 0; ng < 4; ++ng)
        acc[mg][ng] = __builtin_amdgcn_mfma_f32_16x16x32_bf16(af[mg], bff[ng], acc[mg][ng], 0, 0, 0);
    __syncthreads();
  }

  float* O = Out + (size_t)n * BSTRIDE;
  #pragma unroll
  for (int mg = 0; mg < 4; ++mg)
    #pragma unroll
    for (int r = 0; r < 4; ++r) {
      const size_t row = m0 + wm + mg * 16 + l4 * 4 + r;
      const float bb = br[row];
      float* op = O + row * HW + s0 + wn + l15;
      #pragma unroll
      for (int ng = 0; ng < 4; ++ng) op[ng * 16] = acc[mg][ng][r] + bb;
    }
}

extern "C" void kernel_launch(void* const* d_in, const int* in_sizes, int n_in,
                              void* d_out, int out_size, void* d_ws, size_t ws_size,
                              hipStream_t stream)
{
  (void)in_sizes; (void)n_in; (void)out_size; (void)ws_size;
  const float* x  = (const float*)d_in[0];
  const float* Wk = (const float*)d_in[1];
  const float* bk = (const float*)d_in[2];
  const float* Wq = (const float*)d_in[3];
  const float* bq = (const float*)d_in[4];
  const float* Wv = (const float*)d_in[5];
  const float* bv = (const float*)d_in[6];
  const float* Wr = (const float*)d_in[7];
  const float* br = (const float*)d_in[8];

  char* ws = (char*)d_ws;
  u16*   xbT  = (u16*)(ws + oXBT);
  u16*   ek   = (u16*)(ws + oEK);
  u16*   qT   = (u16*)(ws + oQT);
  u16*   vb   = (u16*)(ws + oVB);
  u16*   Wkqv = (u16*)(ws + oWK);
  float* bias = (float*)(ws + oBIAS);
  float* ise  = (float*)(ws + oISE);
  float* ps   = (float*)(ws + oPS);
  float* ctx  = (float*)(ws + oCTX);
  u16*   Mb   = (u16*)(ws + oMB);
  float* cpart= (float*)(ws + oCPART);
  float* mpart= (float*)(ws + oMPART);

  float* attn = (float*)d_out;                    // [8][256][HW]
  float* dctx = (float*)d_out + 33554432;         // [8][32][32]
  float* dmap = (float*)d_out + 33562624;         // [8][HW]

  k_prep<<<64, 256, 0, stream>>>(Wk, Wq, Wv, bk, bq, bv, Wkqv, bias);
  k_transpose<<<dim3(256, 8), 256, 0, stream>>>(x, xbT);
  k_proj<<<6144, 256, 0, stream>>>(Wkqv, xbT, bias, ek, qT, vb, ps);
  k_inv<<<8, 256, 0, stream>>>(ps, ise);
  k_ctx_part<<<4096, 64, 0, stream>>>(ek, vb, ise, cpart, mpart);
  k_ctx_reduce<<<64, 256, 0, stream>>>(cpart, ise, ctx, dctx);
  k_mmat<<<64, 256, 0, stream>>>(ctx, Wr, Mb);
  k_map_reduce<<<128, 256, 0, stream>>>(mpart, dmap);
  k_attn<<<2048, 256, 0, stream>>>(Mb, qT, br, attn);
}